// Round 15
// baseline (111.158 us; speedup 1.0000x reference)
//
#include <hip/hip_runtime.h>
#include <hip/hip_bf16.h>
#include <stdint.h>
#include <stddef.h>

#define SEQ   2048
#define NBATCH 4
#define NHEAD  8
#define DMODEL 512

typedef __attribute__((ext_vector_type(8))) short bf16x8;
typedef __attribute__((ext_vector_type(4))) float f32x4;
typedef __attribute__((ext_vector_type(16))) float f32x16;

#define MFMA16(a, b, c) __builtin_amdgcn_mfma_f32_16x16x32_bf16(a, b, c, 0, 0, 0)
#define MFMA32(a, b, c) __builtin_amdgcn_mfma_f32_32x32x16_bf16(a, b, c, 0, 0, 0)

// 0.125 (softmax scale) * log2(e): QK^T lands in log2 domain -> P = exp2(s)
#define QSCALE 0.18033688011112042f

__device__ __forceinline__ float bf2f(ushort u) {
  union { uint32_t i; float f; } v; v.i = ((uint32_t)u) << 16; return v.f;
}
__device__ __forceinline__ ushort f2bf(float f) {
  union { float f; uint32_t i; } v; v.f = f;
  uint32_t u = v.i;
  return (ushort)((u + 0x7fffu + ((u >> 16) & 1u)) >> 16);
}
__device__ __forceinline__ uint32_t cvtpk(float lo, float hi) {
  uint32_t d;
  asm("v_cvt_pk_bf16_f32 %0, %1, %2" : "=v"(d) : "v"(lo), "v"(hi));
  return d;
}

#if __has_builtin(__builtin_amdgcn_global_load_lds)
__device__ __forceinline__ void gload16(const void* g, void* l) {
  __builtin_amdgcn_global_load_lds(
      (const __attribute__((address_space(1))) void*)g,
      (__attribute__((address_space(3))) void*)l, 16, 0, 0);
}
#define GLOAD_DIRECT 1
#else
#define GLOAD_DIRECT 0
#endif

// ---------------------------------------------------------------------------
// prep_k: fused cvt (x f32 -> xb bf16) + weight transposes.
// Blocks [0,2048): cvt. Blocks [2048,3328): wtrans.
// Wq/Wkv/Wg -> WT in FRAGMENT-MAJOR (B-fragment layout, verified in r7:
// chunk (c5*32+ks)*64 + lane holds col n=c5*32+(lane&31), k=ks*16+(lane>>5)*8+j)
// so the GEMM loads each B MFMA-fragment as ONE coalesced 1 KiB read.
// Wo -> WoT row-major [512][512] (consumed by gemm_o_k's LDS path).
// ---------------------------------------------------------------------------
__global__ __launch_bounds__(256) void prep_k(const float* __restrict__ x,
                                              const float* __restrict__ Wq,
                                              const float* __restrict__ Wkv,
                                              const float* __restrict__ Wg,
                                              const float* __restrict__ Wo,
                                              ushort* __restrict__ xb,
                                              ushort* __restrict__ WT,
                                              ushort* __restrict__ WoT) {
  __shared__ ushort tile[32][33];
  int t = threadIdx.x;
  if (blockIdx.x < 2048) {
    int i = blockIdx.x * 256 + t;
    const float4* p = (const float4*)(x + (size_t)i * 8);
    float4 a = p[0], b = p[1];
    union { int4 v; ushort u[8]; } o;
    o.u[0] = f2bf(a.x); o.u[1] = f2bf(a.y); o.u[2] = f2bf(a.z); o.u[3] = f2bf(a.w);
    o.u[4] = f2bf(b.x); o.u[5] = f2bf(b.y); o.u[6] = f2bf(b.z); o.u[7] = f2bf(b.w);
    *(int4*)(xb + (size_t)i * 8) = o.v;
    return;
  }
  int bidx = blockIdx.x - 2048;
  int bx = bidx % 80, by = bidx / 80;      // by in 0..15
  const float* W;
  int N, nt, base_n;
  bool frag = true;
  if (bx < 16)       { W = Wq;  N = 512;  nt = bx;      base_n = 0; }
  else if (bx < 48)  { W = Wkv; N = 1024; nt = bx - 16; base_n = 512; }
  else if (bx < 64)  { W = Wg;  N = 512;  nt = bx - 48; base_n = 1536; }
  else               { W = Wo;  N = 512;  nt = bx - 64; base_n = 0; frag = false; }
  int n0 = nt * 32, k0 = by * 32;
  int r = t >> 3, c = (t & 7) * 4;
#pragma unroll
  for (int j = 0; j < 4; j++)
    tile[r][c + j] = f2bf(W[(size_t)(k0 + r) * N + n0 + c + j]);
  __syncthreads();
  if (frag) {
    int n = base_n + n0 + r;          // output col (WT row)
    int kbase = k0 + c;               // c % 4 == 0, (c+j)>>3 constant for j<4
    int c5 = n >> 5, l31 = n & 31;
    int ks = kbase >> 4, hi = (kbase >> 3) & 1;
    size_t chunk = (size_t)(c5 * 32 + ks) * 64 + l31 + hi * 32;
#pragma unroll
    for (int j = 0; j < 4; j++)
      WT[chunk * 8 + (kbase & 7) + j] = tile[c + j][r];
  } else {
#pragma unroll
    for (int j = 0; j < 4; j++)
      WoT[(size_t)(n0 + r) * 512 + k0 + c + j] = tile[c + j][r];
  }
}

// ---------------------------------------------------------------------------
// QKVG GEMM, hybrid operand paths (r14 post-mortem: wall = staged_bytes /
// ~5.5 TB/s at 2 blk/CU across 6 structures -> reduce staged bytes):
//   A: verified gload_lds + XOR-swizzle + 2-barrier double-buffer (unchanged).
//   B: fragment-DIRECT from frag-major WT (layout verified r7) -- one
//      coalesced 1 KiB wave-load per fragment, L2-resident, NO barrier
//      constraint so loads prefetch across K-steps under MFMA.
// Staged bytes halve (256 -> 128 MiB); LDS 64 -> 34 KiB.
// 128x128 tile, BK=64, 4 waves (2Mx2N), grid 1024.
// V panel written directly transposed to vT. Fused q/k/v/gates epilogue.
// ---------------------------------------------------------------------------
__global__ __launch_bounds__(256, 2) void gemm128_k(const ushort* __restrict__ A,
                                                    const ushort* __restrict__ Bf,
                                                    ushort* __restrict__ qb,
                                                    ushort* __restrict__ kb,
                                                    ushort* __restrict__ vT,
                                                    ushort* __restrict__ gsb,
                                                    const float* __restrict__ bias) {
  // staging needs 2*128*64 = 16384 ushorts; V-transpose epilogue needs
  // 128*136 = 17408 ushorts. One shared region sized for the max.
  __shared__ __align__(16) ushort Sh[17408];
#define ASB(p) (Sh + (p) * (128 * 64))
  int t = threadIdx.x;
  int nb = gridDim.x * gridDim.y;                 // %8 == 0
  int bid = blockIdx.y * gridDim.x + blockIdx.x;
  int swz = (bid & 7) * (nb >> 3) + (bid >> 3);   // XCD-contiguous panels
  int row0 = (swz / gridDim.x) * 128, col0 = (swz % gridDim.x) * 128;

  int w = t >> 6, l = t & 63, l31 = l & 31, hi = l >> 5;
  int wm = w >> 1, wn = w & 1;                    // 2 x 2 wave grid, 64x64 each
  f32x16 acc[2][2] = {};

  // A staging: thread t covers rows srow + j*32 (j=0..3), 16B slot (t&7).
  int srow = t >> 3;                               // 0..31
  int ssl = (t & 7) ^ (srow & 7);                  // inverse-swizzled global slot
  const ushort* Ag = A + (size_t)(row0 + srow) * 512 + ssl * 8;
  // wave-uniform LDS base slot: lane l lands at slot wslot + l (+ j*256)
  int wslot = __builtin_amdgcn_readfirstlane((t >> 6) << 6);

  // B fragment bases (frag-major): row n-group (col0/32 + wn*2 + cb), lane l.
  const ushort* Bf0 = Bf + ((size_t)((col0 >> 5) + wn * 2 + 0) * 2048 + l) * 8;
  const ushort* Bf1 = Bf + ((size_t)((col0 >> 5) + wn * 2 + 1) * 2048 + l) * 8;

#if GLOAD_DIRECT
#define STG(p, kt)                                                              \
  do {                                                                          \
    gload16(Ag + (size_t)(kt) * 64 + 0 * 32 * 512, ASB(p) + (wslot +   0) * 8); \
    gload16(Ag + (size_t)(kt) * 64 + 1 * 32 * 512, ASB(p) + (wslot + 256) * 8); \
    gload16(Ag + (size_t)(kt) * 64 + 2 * 32 * 512, ASB(p) + (wslot + 512) * 8); \
    gload16(Ag + (size_t)(kt) * 64 + 3 * 32 * 512, ASB(p) + (wslot + 768) * 8); \
  } while (0)
#else
#define STG(p, kt)                                                                  \
  do {                                                                              \
    *(int4*)(ASB(p) + (t +   0) * 8) = *(const int4*)(Ag + (size_t)(kt) * 64);      \
    *(int4*)(ASB(p) + (t + 256) * 8) =                                              \
        *(const int4*)(Ag + (size_t)(kt) * 64 + 1 * 32 * 512);                      \
    *(int4*)(ASB(p) + (t + 512) * 8) =                                              \
        *(const int4*)(Ag + (size_t)(kt) * 64 + 2 * 32 * 512);                      \
    *(int4*)(ASB(p) + (t + 768) * 8) =                                              \
        *(const int4*)(Ag + (size_t)(kt) * 64 + 3 * 32 * 512);                      \
  } while (0)
#endif

// swizzled fragment read: (base, row, 8-elem slot s) -> bf16x8
#define FRAG(Mb, r, s) \
  (*(const bf16x8*)(Mb + ((r) * 64) + ((((s) ^ ((r) & 7))) << 3)))

  STG(0, 0);
  __syncthreads();

#pragma unroll
  for (int kt = 0; kt < 8; kt++) {
    int p = kt & 1;
    if (kt < 7) STG(p ^ 1, kt + 1);

    bf16x8 bfrag[2][4];
#pragma unroll
    for (int kk = 0; kk < 4; kk++) {
      bfrag[0][kk] = *(const bf16x8*)(Bf0 + (kt * 4 + kk) * 512);
      bfrag[1][kk] = *(const bf16x8*)(Bf1 + (kt * 4 + kk) * 512);
    }

    __builtin_amdgcn_s_setprio(1);
#pragma unroll
    for (int rb = 0; rb < 2; rb++) {
      bf16x8 af[4];
#pragma unroll
      for (int kk = 0; kk < 4; kk++)
        af[kk] = FRAG(ASB(p), wm * 64 + rb * 32 + l31, kk * 2 + hi);
#pragma unroll
      for (int kk = 0; kk < 4; kk++) {
        acc[rb][0] = MFMA32(af[kk], bfrag[0][kk], acc[rb][0]);
        acc[rb][1] = MFMA32(af[kk], bfrag[1][kk], acc[rb][1]);
      }
    }
    __builtin_amdgcn_s_setprio(0);

    if (kt < 7) __syncthreads();
  }
#undef STG
#undef FRAG

  // epilogue: C/D 32x32 layout col=lane&31, row=(e&3)+8*(e>>2)+4*hi
  if (col0 >= 1024 && col0 < 1536) {
    // V panel: bf16 transpose via LDS, coalesced 16B stores to vT[bh][64][2048].
    __syncthreads();                 // all waves done with staging LDS
    ushort* lt = Sh;
#pragma unroll
    for (int rb = 0; rb < 2; rb++)
#pragma unroll
      for (int cb = 0; cb < 2; cb++)
#pragma unroll
        for (int e = 0; e < 16; e++) {
          int rr = (e & 3) + 8 * (e >> 2) + 4 * hi;
          int rowL = wm * 64 + rb * 32 + rr;
          int colL = wn * 64 + cb * 32 + l31;
          lt[colL * 136 + rowL] = f2bf(acc[rb][cb][e]);
        }
    __syncthreads();
    int b_ = row0 >> 11;             // batch
    int nb0 = row0 & 2047;           // n base within batch
#pragma unroll
    for (int r = 0; r < 8; r++) {
      int lin = r * 256 + t;         // 0..2047
      int dcol = lin >> 4, n8 = lin & 15;
      int vcol = (col0 - 1024) + dcol;
      int hh = vcol >> 6, dd = vcol & 63;
      bf16x8 v = *(const bf16x8*)(lt + dcol * 136 + n8 * 8);
      *(bf16x8*)(vT + (((size_t)(b_ * 8 + hh) * 64) + dd) * 2048 + nb0 + n8 * 8) = v;
    }
  } else {
#pragma unroll
    for (int rb = 0; rb < 2; rb++) {
#pragma unroll
      for (int cb = 0; cb < 2; cb++) {
#pragma unroll
        for (int e = 0; e < 16; e++) {
          int rr = (e & 3) + 8 * (e >> 2) + 4 * hi;
          int row = row0 + wm * 64 + rb * 32 + rr;
          int col = col0 + wn * 64 + cb * 32 + l31;
          float v = acc[rb][cb][e];
          if (col0 < 512) {
            qb[(size_t)row * 512 + col] = f2bf(v * QSCALE);
          } else if (col0 < 1024) {
            kb[(size_t)row * 512 + (col - 512)] = f2bf(v);
          } else {
            v += bias[col - 1536];
            v = 1.f / (1.f + __expf(-v));
            gsb[(size_t)row * 512 + (col - 1536)] = f2bf(v);
          }
        }
      }
    }
  }
#undef ASB
}

// ---------------------------------------------------------------------------
// Out-projection GEMM: C = gated[8192,512] @ WoT[512,512]^T + bo + x -> f32 y.
// BM=128, BN=64, BK=64 -> grid 512 = 2 blocks/CU. (r13 exact.)
// ---------------------------------------------------------------------------
__global__ __launch_bounds__(256, 2) void gemm_o_k(const ushort* __restrict__ A,
                                                   const ushort* __restrict__ Bt,
                                                   float* __restrict__ yout,
                                                   const float* __restrict__ bias,
                                                   const float* __restrict__ res) {
  __shared__ __align__(16) ushort As[2][128 * 64];   // 32 KiB
  __shared__ __align__(16) ushort Bs[2][64 * 64];    // 16 KiB
  int t = threadIdx.x;
  int nb = gridDim.x * gridDim.y;                 // 512, %8 == 0
  int bid = blockIdx.y * gridDim.x + blockIdx.x;
  int swz = (bid & 7) * (nb >> 3) + (bid >> 3);   // XCD-contiguous panels
  int row0 = (swz / gridDim.x) * 128, col0 = (swz % gridDim.x) * 64;

  int w = t >> 6, l = t & 63, l31 = l & 31, hi = l >> 5;
  int wm = w >> 1, wn = w & 1;                    // 2 x 2 waves, 64x32 each
  f32x16 acc[2] = {};                             // [rb]; single col block

  int srow = t >> 3;                               // 0..31
  int ssl = (t & 7) ^ (srow & 7);                  // inverse-swizzled global slot
  const ushort* Ag = A + (size_t)(row0 + srow) * 512 + ssl * 8;
  const ushort* Bg = Bt + (size_t)(col0 + srow) * 512 + ssl * 8;
  int wslot = __builtin_amdgcn_readfirstlane((t >> 6) << 6);

#if GLOAD_DIRECT
#define STG(p, kt)                                                                \
  do {                                                                            \
    gload16(Ag + (size_t)(kt) * 64 + 0 * 32 * 512, &As[p][(wslot +   0) * 8]);    \
    gload16(Ag + (size_t)(kt) * 64 + 1 * 32 * 512, &As[p][(wslot + 256) * 8]);    \
    gload16(Ag + (size_t)(kt) * 64 + 2 * 32 * 512, &As[p][(wslot + 512) * 8]);    \
    gload16(Ag + (size_t)(kt) * 64 + 3 * 32 * 512, &As[p][(wslot + 768) * 8]);    \
    gload16(Bg + (size_t)(kt) * 64 + 0 * 32 * 512, &Bs[p][(wslot +   0) * 8]);    \
    gload16(Bg + (size_t)(kt) * 64 + 1 * 32 * 512, &Bs[p][(wslot + 256) * 8]);    \
  } while (0)
#else
#define STG(p, kt)                                                                  \
  do {                                                                              \
    *(int4*)(&As[p][(t +   0) * 8]) = *(const int4*)(Ag + (size_t)(kt) * 64);       \
    *(int4*)(&As[p][(t + 256) * 8]) =                                               \
        *(const int4*)(Ag + (size_t)(kt) * 64 + 1 * 32 * 512);                      \
    *(int4*)(&As[p][(t + 512) * 8]) =                                               \
        *(const int4*)(Ag + (size_t)(kt) * 64 + 2 * 32 * 512);                      \
    *(int4*)(&As[p][(t + 768) * 8]) =                                               \
        *(const int4*)(Ag + (size_t)(kt) * 64 + 3 * 32 * 512);                      \
    *(int4*)(&Bs[p][(t +   0) * 8]) = *(const int4*)(Bg + (size_t)(kt) * 64);       \
    *(int4*)(&Bs[p][(t + 256) * 8]) =                                               \
        *(const int4*)(Bg + (size_t)(kt) * 64 + 1 * 32 * 512);                      \
  } while (0)
#endif

#define FRAG(Mb, r, s) \
  (*(const bf16x8*)(&(Mb)[((r) * 64) + ((((s) ^ ((r) & 7))) << 3)]))

  STG(0, 0);
  __syncthreads();

  for (int kt = 0; kt < 8; kt++) {
    int p = kt & 1;
    if (kt < 7) STG(p ^ 1, kt + 1);

    bf16x8 bfrag[4];
#pragma unroll
    for (int kk = 0; kk < 4; kk++)
      bfrag[kk] = FRAG(Bs[p], wn * 32 + l31, kk * 2 + hi);

    __builtin_amdgcn_s_setprio(1);
#pragma unroll
    for (int rb = 0; rb < 2; rb++) {
      bf16x8 af[4];
#pragma unroll
      for (int kk = 0; kk < 4; kk++)
        af[kk] = FRAG(As[p], wm * 64 + rb * 32 + l31, kk * 2 + hi);
#pragma unroll
      for (int kk = 0; kk < 4; kk++)
        acc[rb] = MFMA32(af[kk], bfrag[kk], acc[rb]);
    }
    __builtin_amdgcn_s_setprio(0);

    if (kt < 7) __syncthreads();
  }
#undef STG
#undef FRAG

  // epilogue: C/D 32x32 layout col=lane&31, row=(e&3)+8*(e>>2)+4*hi
#pragma unroll
  for (int rb = 0; rb < 2; rb++) {
#pragma unroll
    for (int e = 0; e < 16; e++) {
      int rr = (e & 3) + 8 * (e >> 2) + 4 * hi;
      int row = row0 + wm * 64 + rb * 32 + rr;
      int col = col0 + wn * 32 + l31;
      float v = acc[rb][e] + bias[col] + res[(size_t)row * 512 + col];
      yout[(size_t)row * 512 + col] = v;
    }
  }
}

// ---------------------------------------------------------------------------
// Flash attention, 32x32 MFMA, swapped QK^T, exp2 softmax (no max-tracking).
// KVBLK=128 as TWO 64-j subtiles per staged tile (r14 exact).
// LDS 72 KiB, 1 block/CU (grid 256). lsum via MFMA ones-column (acco2).
// ---------------------------------------------------------------------------
__global__ __launch_bounds__(512) void attn_k(const ushort* __restrict__ q,
                                              const ushort* __restrict__ kbuf,
                                              const ushort* __restrict__ vT,
                                              const ushort* __restrict__ gs,
                                              ushort* __restrict__ gated) {
  __shared__ __align__(16) ushort Kl[2][2][64][72];
  __shared__ __align__(16) ushort Vl[2][2][64][72];   // [buf][jhalf][d][j]
  int t = threadIdx.x;
  int bid = blockIdx.x;
  int swz = (bid & 7) * 32 + (bid >> 3);        // XCD swizzle (256 % 8 == 0)
  int qt = swz & 7, bh = swz >> 3;              // 8 q-tiles x 32 bh
  int b = bh >> 3, h = bh & 7;
  int q0 = qt * 256;
  int w = t >> 6, l = t & 63;                    // w in 0..7
  int l31 = l & 31, hi = l >> 5;
  size_t base_n = (size_t)b * SEQ;

  const ushort* qp = q + (base_n + q0 + w * 32 + l31) * 512 + h * 64 + hi * 8;
  bf16x8 qf[4];
#pragma unroll
  for (int kd = 0; kd < 4; kd++)
    qf[kd] = *(const bf16x8*)(qp + kd * 16);

  bf16x8 vones;
#pragma unroll
  for (int j = 0; j < 8; j++) vones[j] = (short)0x3F80;  // bf16 1.0

  f32x16 acco0 = {}, acco1 = {}, acco2 = {};

  // staging: 512 threads; per 128-tile each thread carries 2 K rows + 2 V rows.
  int srow = t >> 3, c8 = (t & 7) * 8;
  const ushort* kg = kbuf + (base_n + srow) * 512 + h * 64 + c8;
  const ushort* vg = vT + ((size_t)bh * 64 + srow) * 2048 + c8;

#define QK_PHASE(KB, S0, S1)                                                   \
  do {                                                                         \
    _Pragma("unroll")                                                          \
    for (int kd = 0; kd < 4; kd++) {                                           \
      bf16x8 k0 = *(const bf16x8*)((KB) + l31 * 144 + kd * 32 + hi * 16);      \
      bf16x8 k1 = *(const bf16x8*)((KB) + (32 + l31) * 144 + kd * 32 + hi * 16);\
      S0 = MFMA32(k0, qf[kd], S0);                                             \
      S1 = MFMA32(k1, qf[kd], S1);                                             \
    }                                                                          \
  } while (0)

#define SM_PHASE(S0, S1, PK)                                                   \
  do {                                                                         \
    _Pragma("unroll")                                                          \
    for (int sg = 0; sg < 4; sg++) {                                           \
      _Pragma("unroll")                                                        \
      for (int u = 0; u < 2; u++) {                                            \
        float a = __builtin_amdgcn_exp2f(S0[(sg << 2) | (u << 1)]);            \
        float c = __builtin_amdgcn_exp2f(S0[(sg << 2) | (u << 1) | 1]);        \
        PK[sg * 2 + u] = cvtpk(a, c);                                          \
      }                                                                        \
    }                                                                          \
    _Pragma("unroll")                                                          \
    for (int sg = 0; sg < 4; sg++) {                                           \
      _Pragma("unroll")                                                        \
      for (int u = 0; u < 2; u++) {                                            \
        float a = __builtin_amdgcn_exp2f(S1[(sg << 2) | (u << 1)]);            \
        float c = __builtin_amdgcn_exp2f(S1[(sg << 2) | (u << 1) | 1]);        \
        PK[8 + sg * 2 + u] = cvtpk(a, c);                                      \
      }                                                                        \
    }                                                                          \
  } while (0)

#define PV_PHASE(VB, PK)                                                       \
  do {                                                                         \
    _Pragma("unroll")                                                          \
    for (int jk = 0; jk < 4; jk++) {                                           \
      uint32_t x0 = PK[(2 * jk) * 2 + 0], y0 = PK[(2 * jk + 1) * 2 + 0];       \
      uint32_t x1 = PK[(2 * jk) * 2 + 1], y1 = PK[(2 * jk + 1) * 2 + 1];       \
      asm("v_permlane32_swap_b32 %0, %1" : "+v"(x0), "+v"(y0));                \
      asm("v_permlane32_swap_b32 %0, %1" : "+v"(x1), "+v"(y1));                \
      union { bf16x8 v; uint32_t u[4]; } pa;                                   \
      pa.u[0] = x0; pa.u[1] = x1; pa.u[2] = y0; pa.u[3] = y1;                  \
      bf16x8 v0 = *(const bf16x8*)((VB) + l31 * 144 + jk * 32 + hi * 16);      \
      bf16x8 v1 = *(const bf16x8*)((VB) + (32 + l31) * 144 + jk * 32 + hi * 16);\
      acco0 = MFMA32(pa.v, v0, acco0);                                         \
      acco1 = MFMA32(pa.v, v1, acco1);                                         \
      acco2 = MFMA32(pa.v, vones, acco2);                                      \
    }                                                                          \
  } while (0)

#define STAGE_LDS(pp)                                                          \
  do {                                                                         \
    *(int4*)((char*)Kl[pp][0] + srow * 144 + c8 * 2) = kA;                     \
    *(int4*)((char*)Kl[pp][1] + srow * 144 + c8 * 2) = kB;                     \
    *(int4*)((char*)Vl[pp][0] + srow * 144 + c8 * 2) = vA;                     \
    *(int4*)((char*)Vl[pp][1] + srow * 144 + c8 * 2) = vB;                     \
  } while (0)

#define LOADT(n)                                                               \
  do {                                                                         \
    kA = *(const int4*)(kg + (size_t)(n) * 128 * 512);                         \
    kB = *(const int4*)(kg + ((size_t)(n) * 128 + 64) * 512);                  \
    vA = *(const int4*)(vg + (n) * 128);                                       \
    vB = *(const int4*)(vg + (n) * 128 + 64);                                  \
  } while (0)

  // prologue: tile 0 -> LDS buf0; tile 1 -> regs
  int4 kA, kB, vA, vB;
  LOADT(0);
  STAGE_LDS(0);
  LOADT(1);
  __syncthreads();

  int p = 0;
  const int NT = SEQ / 128;                      // 16 tiles
  for (int jt = 0; jt < NT; jt++) {
    // ---- j-half 0 ----
    f32x16 s0 = {}, s1 = {};
    __builtin_amdgcn_s_setprio(1);
    QK_PHASE((const char*)Kl[p][0], s0, s1);
    __builtin_amdgcn_s_setprio(0);
    if (jt < NT - 1) STAGE_LDS(p ^ 1);           // overlaps SM/PV below
    {
      uint32_t pk[16];
      SM_PHASE(s0, s1, pk);
      __builtin_amdgcn_s_setprio(1);
      PV_PHASE((const char*)Vl[p][0], pk);
      __builtin_amdgcn_s_setprio(0);
    }
    // ---- j-half 1 ----
    s0 = (f32x16){}; s1 = (f32x16){};
    __builtin_amdgcn_s_setprio(1);
    QK_PHASE((const char*)Kl[p][1], s0, s1);
    __builtin_amdgcn_s_setprio(0);
    {
      uint32_t pk[16];
      SM_PHASE(s0, s1, pk);
      __builtin_amdgcn_s_setprio(1);
      PV_PHASE((const char*)Vl[p][1], pk);
      __builtin_amdgcn_s_setprio(0);
    }

    if (jt < NT - 1) {
      __syncthreads();
      if (jt < NT - 2) LOADT(jt + 2);
      p ^= 1;
    }
  }
#undef QK_PHASE
#undef SM_PHASE
#undef PV_PHASE
#undef STAGE_LDS
#undef LOADT

#pragma unroll
  for (int e = 0; e < 16; e++) {
    int qr = (e & 3) + 8 * (e >> 2) + 4 * hi;
    size_t row = base_n + q0 + w * 32 + qr;
    int col = h * 64 + l31;
    float rcp = 1.f / acco2[e];
    float v0 = acco0[e] * rcp * bf2f(gs[row * 512 + col]);
    float v1 = acco1[e] * rcp * bf2f(gs[row * 512 + col + 32]);
    gated[row * 512 + col] = f2bf(v0);
    gated[row * 512 + col + 32] = f2bf(v1);
  }
}

// ---------------------------------------------------------------------------
// LayerNorm over rows of 512, f32 in/out, wave per row.
// ---------------------------------------------------------------------------
__global__ __launch_bounds__(256) void ln_k(const float* __restrict__ y,
                                            const float* __restrict__ gamma,
                                            const float* __restrict__ beta,
                                            float* __restrict__ out) {
  int w = threadIdx.x >> 6, l = threadIdx.x & 63;
  size_t row = (size_t)blockIdx.x * 4 + w;
  const float4* yp = (const float4*)(y + row * 512);
  float4 a = yp[l * 2], b = yp[l * 2 + 1];
  float f[8] = {a.x, a.y, a.z, a.w, b.x, b.y, b.z, b.w};
  float sm = 0.f, sq = 0.f;
#pragma unroll
  for (int j = 0; j < 8; j++) { sm += f[j]; sq += f[j] * f[j]; }
#pragma unroll
  for (int off = 1; off < 64; off <<= 1) {
    sm += __shfl_xor(sm, off);
    sq += __shfl_xor(sq, off);
  }
  float mean = sm * (1.f / 512.f);
  float var = sq * (1.f / 512.f) - mean * mean;
  float rs = rsqrtf(var + 1e-5f);
  float4 g0 = ((const float4*)gamma)[l * 2], g1 = ((const float4*)gamma)[l * 2 + 1];
  float4 b0 = ((const float4*)beta)[l * 2],  b1 = ((const float4*)beta)[l * 2 + 1];
  float4 o0, o1;
  o0.x = (f[0] - mean) * rs * g0.x + b0.x;
  o0.y = (f[1] - mean) * rs * g0.y + b0.y;
  o0.z = (f[2] - mean) * rs * g0.z + b0.z;
  o0.w = (f[3] - mean) * rs * g0.w + b0.w;
  o1.x = (f[4] - mean) * rs * g1.x + b1.x;
  o1.y = (f[5] - mean) * rs * g1.y + b1.y;
  o1.z = (f[6] - mean) * rs * g1.z + b1.z;
  o1.w = (f[7] - mean) * rs * g1.w + b1.w;
  float4* op = (float4*)(out + row * 512);
  op[l * 2] = o0;
  op[l * 2 + 1] = o1;
}

// ---------------------------------------------------------------------------
extern "C" void kernel_launch(void* const* d_in, const int* in_sizes, int n_in,
                              void* d_out, int out_size, void* d_ws, size_t ws_size,
                              hipStream_t stream) {
  (void)in_sizes; (void)n_in; (void)out_size; (void)ws_size;
  const float* x     = (const float*)d_in[0];
  const float* Wq    = (const float*)d_in[1];
  const float* Wkv   = (const float*)d_in[2];
  const float* Wo    = (const float*)d_in[3];
  const float* bo    = (const float*)d_in[4];
  const float* Wg    = (const float*)d_in[5];
  const float* bg    = (const float*)d_in[6];
  const float* gamma = (const float*)d_in[7];
  const float* beta  = (const float*)d_in[8];

  char* ws = (char*)d_ws;
  ushort* xb    = (ushort*)(ws);                    //  8 MiB
  ushort* qbuf  = (ushort*)(ws + (8u  << 20));      //  8 MiB
  ushort* kbuf  = (ushort*)(ws + (16u << 20));      //  8 MiB
  ushort* vT    = (ushort*)(ws + (32u << 20));      //  8 MiB [bh][64][2048]
  ushort* gsb   = (ushort*)(ws + (40u << 20));      //  8 MiB
  ushort* gated = (ushort*)(ws + (48u << 20));      //  8 MiB
  float*  y     = (float*)(ws + (56u << 20));       // 16 MiB
  ushort* WT    = (ushort*)(ws + (72u << 20));      //  2 MiB (frag-major)
  ushort* WoT   = (ushort*)(ws + (74u << 20));      // 0.5 MiB [512][512]

  // fused x-convert + weight transposes (WT frag-major, WoT row-major)
  prep_k<<<2048 + 1280, 256, 0, stream>>>(x, Wq, Wkv, Wg, Wo, xb, WT, WoT);

  // fused q/k/v/gates projection: A via LDS, B frag-direct from L2.
  // V panel lands directly transposed in vT.
  gemm128_k<<<dim3(16, 64), 256, 0, stream>>>(xb, WT, qbuf, kbuf, vT, gsb, bg);

  attn_k<<<256, 512, 0, stream>>>(qbuf, kbuf, vT, gsb, gated);

  // out-projection: 128x64 tiles -> 512 blocks = 2 blocks/CU
  gemm_o_k<<<dim3(8, 64), 256, 0, stream>>>(gated, WoT, y, bo, x);

  ln_k<<<(NBATCH * SEQ) / 4, 256, 0, stream>>>(y, gamma, beta, (float*)d_out);
}

// Round 16
// 110.611 us; speedup vs baseline: 1.0049x; 1.0049x over previous
//
#include <hip/hip_runtime.h>
#include <hip/hip_bf16.h>
#include <stdint.h>
#include <stddef.h>

#define SEQ   2048
#define NBATCH 4
#define NHEAD  8
#define DMODEL 512

typedef __attribute__((ext_vector_type(8))) short bf16x8;
typedef __attribute__((ext_vector_type(4))) float f32x4;
typedef __attribute__((ext_vector_type(16))) float f32x16;

#define MFMA16(a, b, c) __builtin_amdgcn_mfma_f32_16x16x32_bf16(a, b, c, 0, 0, 0)
#define MFMA32(a, b, c) __builtin_amdgcn_mfma_f32_32x32x16_bf16(a, b, c, 0, 0, 0)

// 0.125 (softmax scale) * log2(e): QK^T lands in log2 domain -> P = exp2(s)
#define QSCALE 0.18033688011112042f

__device__ __forceinline__ float bf2f(ushort u) {
  union { uint32_t i; float f; } v; v.i = ((uint32_t)u) << 16; return v.f;
}
__device__ __forceinline__ ushort f2bf(float f) {
  union { float f; uint32_t i; } v; v.f = f;
  uint32_t u = v.i;
  return (ushort)((u + 0x7fffu + ((u >> 16) & 1u)) >> 16);
}
__device__ __forceinline__ uint32_t cvtpk(float lo, float hi) {
  uint32_t d;
  asm("v_cvt_pk_bf16_f32 %0, %1, %2" : "=v"(d) : "v"(lo), "v"(hi));
  return d;
}

#if __has_builtin(__builtin_amdgcn_global_load_lds)
__device__ __forceinline__ void gload16(const void* g, void* l) {
  __builtin_amdgcn_global_load_lds(
      (const __attribute__((address_space(1))) void*)g,
      (__attribute__((address_space(3))) void*)l, 16, 0, 0);
}
#define GLOAD_DIRECT 1
#else
#define GLOAD_DIRECT 0
#endif

// ---------------------------------------------------------------------------
// prep_k: fused cvt (x f32 -> xb bf16) + all four weight transposes.
// Blocks [0,2048): cvt. Blocks [2048,3328): wtrans (flattened 80x16).
// ---------------------------------------------------------------------------
__global__ __launch_bounds__(256) void prep_k(const float* __restrict__ x,
                                              const float* __restrict__ Wq,
                                              const float* __restrict__ Wkv,
                                              const float* __restrict__ Wg,
                                              const float* __restrict__ Wo,
                                              ushort* __restrict__ xb,
                                              ushort* __restrict__ WT,
                                              ushort* __restrict__ WoT) {
  __shared__ ushort tile[32][33];
  int t = threadIdx.x;
  if (blockIdx.x < 2048) {
    int i = blockIdx.x * 256 + t;
    const float4* p = (const float4*)(x + (size_t)i * 8);
    float4 a = p[0], b = p[1];
    union { int4 v; ushort u[8]; } o;
    o.u[0] = f2bf(a.x); o.u[1] = f2bf(a.y); o.u[2] = f2bf(a.z); o.u[3] = f2bf(a.w);
    o.u[4] = f2bf(b.x); o.u[5] = f2bf(b.y); o.u[6] = f2bf(b.z); o.u[7] = f2bf(b.w);
    *(int4*)(xb + (size_t)i * 8) = o.v;
    return;
  }
  int bidx = blockIdx.x - 2048;
  int bx = bidx % 80, by = bidx / 80;      // by in 0..15
  const float* W;
  ushort* dst;
  int N, nt;
  if (bx < 16)       { W = Wq;  dst = WT;              N = 512;  nt = bx; }
  else if (bx < 48)  { W = Wkv; dst = WT + 512 * 512;  N = 1024; nt = bx - 16; }
  else if (bx < 64)  { W = Wg;  dst = WT + 1536 * 512; N = 512;  nt = bx - 48; }
  else               { W = Wo;  dst = WoT;             N = 512;  nt = bx - 64; }
  int n0 = nt * 32, k0 = by * 32;
  int r = t >> 3, c = (t & 7) * 4;
#pragma unroll
  for (int j = 0; j < 4; j++)
    tile[r][c + j] = f2bf(W[(size_t)(k0 + r) * N + n0 + c + j]);
  __syncthreads();
#pragma unroll
  for (int j = 0; j < 4; j++)
    dst[(size_t)(n0 + r) * 512 + k0 + c + j] = tile[c + j][r];
}

// ---------------------------------------------------------------------------
// GEMM, 128x128 tile, BK=64, 4 waves (2Mx2N), 32x32x16 MFMA (r11 exact:
// grid 1024 -> 2 blocks/CU; V panel written directly transposed to vT).
// Fused q/k/v/gates epilogue.
// ---------------------------------------------------------------------------
__global__ __launch_bounds__(256, 2) void gemm128_k(const ushort* __restrict__ A,
                                                    const ushort* __restrict__ Bt,
                                                    ushort* __restrict__ qb,
                                                    ushort* __restrict__ kb,
                                                    ushort* __restrict__ vT,
                                                    ushort* __restrict__ gsb,
                                                    const float* __restrict__ bias) {
  __shared__ __align__(16) ushort Sh[4 * 128 * 64];   // 64 KiB: As[2] | Bs[2]
#define ASB(p) (Sh + (p) * (128 * 64))
#define BSB(p) (Sh + 2 * (128 * 64) + (p) * (128 * 64))
  int t = threadIdx.x;
  int nb = gridDim.x * gridDim.y;                 // %8 == 0
  int bid = blockIdx.y * gridDim.x + blockIdx.x;
  int swz = (bid & 7) * (nb >> 3) + (bid >> 3);   // XCD-contiguous panels
  int row0 = (swz / gridDim.x) * 128, col0 = (swz % gridDim.x) * 128;

  int w = t >> 6, l = t & 63, l31 = l & 31, hi = l >> 5;
  int wm = w >> 1, wn = w & 1;                    // 2 x 2 wave grid, 64x64 each
  f32x16 acc[2][2] = {};

  // staging: thread t covers rows srow + j*32 (j=0..3), 16B slot (t&7).
  int srow = t >> 3;                               // 0..31
  int ssl = (t & 7) ^ (srow & 7);                  // inverse-swizzled global slot
  const ushort* Ag = A + (size_t)(row0 + srow) * 512 + ssl * 8;
  const ushort* Bg = Bt + (size_t)(col0 + srow) * 512 + ssl * 8;
  // wave-uniform LDS base slot: lane l lands at slot wslot + l (+ j*256)
  int wslot = __builtin_amdgcn_readfirstlane((t >> 6) << 6);

#if GLOAD_DIRECT
#define STG(p, kt)                                                              \
  do {                                                                          \
    gload16(Ag + (size_t)(kt) * 64 + 0 * 32 * 512, ASB(p) + (wslot +   0) * 8); \
    gload16(Ag + (size_t)(kt) * 64 + 1 * 32 * 512, ASB(p) + (wslot + 256) * 8); \
    gload16(Ag + (size_t)(kt) * 64 + 2 * 32 * 512, ASB(p) + (wslot + 512) * 8); \
    gload16(Ag + (size_t)(kt) * 64 + 3 * 32 * 512, ASB(p) + (wslot + 768) * 8); \
    gload16(Bg + (size_t)(kt) * 64 + 0 * 32 * 512, BSB(p) + (wslot +   0) * 8); \
    gload16(Bg + (size_t)(kt) * 64 + 1 * 32 * 512, BSB(p) + (wslot + 256) * 8); \
    gload16(Bg + (size_t)(kt) * 64 + 2 * 32 * 512, BSB(p) + (wslot + 512) * 8); \
    gload16(Bg + (size_t)(kt) * 64 + 3 * 32 * 512, BSB(p) + (wslot + 768) * 8); \
  } while (0)
#else
#define STG(p, kt)                                                                  \
  do {                                                                              \
    *(int4*)(ASB(p) + (t +   0) * 8) = *(const int4*)(Ag + (size_t)(kt) * 64);      \
    *(int4*)(ASB(p) + (t + 256) * 8) =                                              \
        *(const int4*)(Ag + (size_t)(kt) * 64 + 1 * 32 * 512);                      \
    *(int4*)(ASB(p) + (t + 512) * 8) =                                              \
        *(const int4*)(Ag + (size_t)(kt) * 64 + 2 * 32 * 512);                      \
    *(int4*)(ASB(p) + (t + 768) * 8) =                                              \
        *(const int4*)(Ag + (size_t)(kt) * 64 + 3 * 32 * 512);                      \
    *(int4*)(BSB(p) + (t +   0) * 8) = *(const int4*)(Bg + (size_t)(kt) * 64);      \
    *(int4*)(BSB(p) + (t + 256) * 8) =                                              \
        *(const int4*)(Bg + (size_t)(kt) * 64 + 1 * 32 * 512);                      \
    *(int4*)(BSB(p) + (t + 512) * 8) =                                              \
        *(const int4*)(Bg + (size_t)(kt) * 64 + 2 * 32 * 512);                      \
    *(int4*)(BSB(p) + (t + 768) * 8) =                                              \
        *(const int4*)(Bg + (size_t)(kt) * 64 + 3 * 32 * 512);                      \
  } while (0)
#endif

// swizzled fragment read: (base, row, 8-elem slot s) -> bf16x8
#define FRAG(Mb, r, s) \
  (*(const bf16x8*)(Mb + ((r) * 64) + ((((s) ^ ((r) & 7))) << 3)))

  STG(0, 0);
  __syncthreads();

  for (int kt = 0; kt < 8; kt++) {
    int p = kt & 1;
    if (kt < 7) STG(p ^ 1, kt + 1);

    bf16x8 bfrag[2][4];
#pragma unroll
    for (int cb = 0; cb < 2; cb++)
#pragma unroll
      for (int kk = 0; kk < 4; kk++)
        bfrag[cb][kk] = FRAG(BSB(p), wn * 64 + cb * 32 + l31, kk * 2 + hi);

    __builtin_amdgcn_s_setprio(1);
#pragma unroll
    for (int rb = 0; rb < 2; rb++) {
      bf16x8 af[4];
#pragma unroll
      for (int kk = 0; kk < 4; kk++)
        af[kk] = FRAG(ASB(p), wm * 64 + rb * 32 + l31, kk * 2 + hi);
#pragma unroll
      for (int kk = 0; kk < 4; kk++) {
        acc[rb][0] = MFMA32(af[kk], bfrag[0][kk], acc[rb][0]);
        acc[rb][1] = MFMA32(af[kk], bfrag[1][kk], acc[rb][1]);
      }
    }
    __builtin_amdgcn_s_setprio(0);

    if (kt < 7) __syncthreads();
  }
#undef STG
#undef FRAG

  // epilogue: C/D 32x32 layout col=lane&31, row=(e&3)+8*(e>>2)+4*hi
  if (col0 >= 1024 && col0 < 1536) {
    // V panel: bf16 transpose via LDS, coalesced 16B stores to vT[bh][64][2048].
    __syncthreads();                 // all waves done with staging LDS
    ushort* lt = Sh;
#pragma unroll
    for (int rb = 0; rb < 2; rb++)
#pragma unroll
      for (int cb = 0; cb < 2; cb++)
#pragma unroll
        for (int e = 0; e < 16; e++) {
          int rr = (e & 3) + 8 * (e >> 2) + 4 * hi;
          int rowL = wm * 64 + rb * 32 + rr;
          int colL = wn * 64 + cb * 32 + l31;
          lt[colL * 136 + rowL] = f2bf(acc[rb][cb][e]);
        }
    __syncthreads();
    int b_ = row0 >> 11;             // batch
    int nb0 = row0 & 2047;           // n base within batch
#pragma unroll
    for (int r = 0; r < 8; r++) {
      int lin = r * 256 + t;         // 0..2047
      int dcol = lin >> 4, n8 = lin & 15;
      int vcol = (col0 - 1024) + dcol;
      int hh = vcol >> 6, dd = vcol & 63;
      bf16x8 v = *(const bf16x8*)(lt + dcol * 136 + n8 * 8);
      *(bf16x8*)(vT + (((size_t)(b_ * 8 + hh) * 64) + dd) * 2048 + nb0 + n8 * 8) = v;
    }
  } else {
#pragma unroll
    for (int rb = 0; rb < 2; rb++) {
#pragma unroll
      for (int cb = 0; cb < 2; cb++) {
#pragma unroll
        for (int e = 0; e < 16; e++) {
          int rr = (e & 3) + 8 * (e >> 2) + 4 * hi;
          int row = row0 + wm * 64 + rb * 32 + rr;
          int col = col0 + wn * 64 + cb * 32 + l31;
          float v = acc[rb][cb][e];
          if (col0 < 512) {
            qb[(size_t)row * 512 + col] = f2bf(v * QSCALE);
          } else if (col0 < 1024) {
            kb[(size_t)row * 512 + (col - 512)] = f2bf(v);
          } else {
            v += bias[col - 1536];
            v = 1.f / (1.f + __expf(-v));
            gsb[(size_t)row * 512 + (col - 1536)] = f2bf(v);
          }
        }
      }
    }
  }
#undef ASB
#undef BSB
}

// ---------------------------------------------------------------------------
// Out-projection GEMM: C = gated[8192,512] @ WoT[512,512]^T + bo + x -> f32 y.
// BM=128, BN=64, BK=64 -> grid 512 = 2 blocks/CU. (r13 exact.)
// ---------------------------------------------------------------------------
__global__ __launch_bounds__(256, 2) void gemm_o_k(const ushort* __restrict__ A,
                                                   const ushort* __restrict__ Bt,
                                                   float* __restrict__ yout,
                                                   const float* __restrict__ bias,
                                                   const float* __restrict__ res) {
  __shared__ __align__(16) ushort As[2][128 * 64];   // 32 KiB
  __shared__ __align__(16) ushort Bs[2][64 * 64];    // 16 KiB
  int t = threadIdx.x;
  int nb = gridDim.x * gridDim.y;                 // 512, %8 == 0
  int bid = blockIdx.y * gridDim.x + blockIdx.x;
  int swz = (bid & 7) * (nb >> 3) + (bid >> 3);   // XCD-contiguous panels
  int row0 = (swz / gridDim.x) * 128, col0 = (swz % gridDim.x) * 64;

  int w = t >> 6, l = t & 63, l31 = l & 31, hi = l >> 5;
  int wm = w >> 1, wn = w & 1;                    // 2 x 2 waves, 64x32 each
  f32x16 acc[2] = {};                             // [rb]; single col block

  int srow = t >> 3;                               // 0..31
  int ssl = (t & 7) ^ (srow & 7);                  // inverse-swizzled global slot
  const ushort* Ag = A + (size_t)(row0 + srow) * 512 + ssl * 8;
  const ushort* Bg = Bt + (size_t)(col0 + srow) * 512 + ssl * 8;
  int wslot = __builtin_amdgcn_readfirstlane((t >> 6) << 6);

#if GLOAD_DIRECT
#define STG(p, kt)                                                                \
  do {                                                                            \
    gload16(Ag + (size_t)(kt) * 64 + 0 * 32 * 512, &As[p][(wslot +   0) * 8]);    \
    gload16(Ag + (size_t)(kt) * 64 + 1 * 32 * 512, &As[p][(wslot + 256) * 8]);    \
    gload16(Ag + (size_t)(kt) * 64 + 2 * 32 * 512, &As[p][(wslot + 512) * 8]);    \
    gload16(Ag + (size_t)(kt) * 64 + 3 * 32 * 512, &As[p][(wslot + 768) * 8]);    \
    gload16(Bg + (size_t)(kt) * 64 + 0 * 32 * 512, &Bs[p][(wslot +   0) * 8]);    \
    gload16(Bg + (size_t)(kt) * 64 + 1 * 32 * 512, &Bs[p][(wslot + 256) * 8]);    \
  } while (0)
#else
#define STG(p, kt)                                                                  \
  do {                                                                              \
    *(int4*)(&As[p][(t +   0) * 8]) = *(const int4*)(Ag + (size_t)(kt) * 64);       \
    *(int4*)(&As[p][(t + 256) * 8]) =                                               \
        *(const int4*)(Ag + (size_t)(kt) * 64 + 1 * 32 * 512);                      \
    *(int4*)(&As[p][(t + 512) * 8]) =                                               \
        *(const int4*)(Ag + (size_t)(kt) * 64 + 2 * 32 * 512);                      \
    *(int4*)(&As[p][(t + 768) * 8]) =                                               \
        *(const int4*)(Ag + (size_t)(kt) * 64 + 3 * 32 * 512);                      \
    *(int4*)(&Bs[p][(t +   0) * 8]) = *(const int4*)(Bg + (size_t)(kt) * 64);       \
    *(int4*)(&Bs[p][(t + 256) * 8]) =                                               \
        *(const int4*)(Bg + (size_t)(kt) * 64 + 1 * 32 * 512);                      \
  } while (0)
#endif

#define FRAG(Mb, r, s) \
  (*(const bf16x8*)(&(Mb)[((r) * 64) + ((((s) ^ ((r) & 7))) << 3)]))

  STG(0, 0);
  __syncthreads();

  for (int kt = 0; kt < 8; kt++) {
    int p = kt & 1;
    if (kt < 7) STG(p ^ 1, kt + 1);

    bf16x8 bfrag[4];
#pragma unroll
    for (int kk = 0; kk < 4; kk++)
      bfrag[kk] = FRAG(Bs[p], wn * 32 + l31, kk * 2 + hi);

    __builtin_amdgcn_s_setprio(1);
#pragma unroll
    for (int rb = 0; rb < 2; rb++) {
      bf16x8 af[4];
#pragma unroll
      for (int kk = 0; kk < 4; kk++)
        af[kk] = FRAG(As[p], wm * 64 + rb * 32 + l31, kk * 2 + hi);
#pragma unroll
      for (int kk = 0; kk < 4; kk++)
        acc[rb] = MFMA32(af[kk], bfrag[kk], acc[rb]);
    }
    __builtin_amdgcn_s_setprio(0);

    if (kt < 7) __syncthreads();
  }
#undef STG
#undef FRAG

  // epilogue: C/D 32x32 layout col=lane&31, row=(e&3)+8*(e>>2)+4*hi
#pragma unroll
  for (int rb = 0; rb < 2; rb++) {
#pragma unroll
    for (int e = 0; e < 16; e++) {
      int rr = (e & 3) + 8 * (e >> 2) + 4 * hi;
      int row = row0 + wm * 64 + rb * 32 + rr;
      int col = col0 + wn * 32 + l31;
      float v = acc[rb][e] + bias[col] + res[(size_t)row * 512 + col];
      yout[(size_t)row * 512 + col] = v;
    }
  }
}

// ---------------------------------------------------------------------------
// Flash attention, 32x32 MFMA, swapped QK^T, exp2 softmax (no max-tracking).
// KVBLK=128 as TWO 64-j subtiles per staged tile (r14 exact).
// LDS 72 KiB, 1 block/CU (grid 256). lsum via MFMA ones-column (acco2).
// ---------------------------------------------------------------------------
__global__ __launch_bounds__(512) void attn_k(const ushort* __restrict__ q,
                                              const ushort* __restrict__ kbuf,
                                              const ushort* __restrict__ vT,
                                              const ushort* __restrict__ gs,
                                              ushort* __restrict__ gated) {
  __shared__ __align__(16) ushort Kl[2][2][64][72];
  __shared__ __align__(16) ushort Vl[2][2][64][72];   // [buf][jhalf][d][j]
  int t = threadIdx.x;
  int bid = blockIdx.x;
  int swz = (bid & 7) * 32 + (bid >> 3);        // XCD swizzle (256 % 8 == 0)
  int qt = swz & 7, bh = swz >> 3;              // 8 q-tiles x 32 bh
  int b = bh >> 3, h = bh & 7;
  int q0 = qt * 256;
  int w = t >> 6, l = t & 63;                    // w in 0..7
  int l31 = l & 31, hi = l >> 5;
  size_t base_n = (size_t)b * SEQ;

  const ushort* qp = q + (base_n + q0 + w * 32 + l31) * 512 + h * 64 + hi * 8;
  bf16x8 qf[4];
#pragma unroll
  for (int kd = 0; kd < 4; kd++)
    qf[kd] = *(const bf16x8*)(qp + kd * 16);

  bf16x8 vones;
#pragma unroll
  for (int j = 0; j < 8; j++) vones[j] = (short)0x3F80;  // bf16 1.0

  f32x16 acco0 = {}, acco1 = {}, acco2 = {};

  // staging: 512 threads; per 128-tile each thread carries 2 K rows + 2 V rows.
  int srow = t >> 3, c8 = (t & 7) * 8;
  const ushort* kg = kbuf + (base_n + srow) * 512 + h * 64 + c8;
  const ushort* vg = vT + ((size_t)bh * 64 + srow) * 2048 + c8;

#define QK_PHASE(KB, S0, S1)                                                   \
  do {                                                                         \
    _Pragma("unroll")                                                          \
    for (int kd = 0; kd < 4; kd++) {                                           \
      bf16x8 k0 = *(const bf16x8*)((KB) + l31 * 144 + kd * 32 + hi * 16);      \
      bf16x8 k1 = *(const bf16x8*)((KB) + (32 + l31) * 144 + kd * 32 + hi * 16);\
      S0 = MFMA32(k0, qf[kd], S0);                                             \
      S1 = MFMA32(k1, qf[kd], S1);                                             \
    }                                                                          \
  } while (0)

#define SM_PHASE(S0, S1, PK)                                                   \
  do {                                                                         \
    _Pragma("unroll")                                                          \
    for (int sg = 0; sg < 4; sg++) {                                           \
      _Pragma("unroll")                                                        \
      for (int u = 0; u < 2; u++) {                                            \
        float a = __builtin_amdgcn_exp2f(S0[(sg << 2) | (u << 1)]);            \
        float c = __builtin_amdgcn_exp2f(S0[(sg << 2) | (u << 1) | 1]);        \
        PK[sg * 2 + u] = cvtpk(a, c);                                          \
      }                                                                        \
    }                                                                          \
    _Pragma("unroll")                                                          \
    for (int sg = 0; sg < 4; sg++) {                                           \
      _Pragma("unroll")                                                        \
      for (int u = 0; u < 2; u++) {                                            \
        float a = __builtin_amdgcn_exp2f(S1[(sg << 2) | (u << 1)]);            \
        float c = __builtin_amdgcn_exp2f(S1[(sg << 2) | (u << 1) | 1]);        \
        PK[8 + sg * 2 + u] = cvtpk(a, c);                                      \
      }                                                                        \
    }                                                                          \
  } while (0)

#define PV_PHASE(VB, PK)                                                       \
  do {                                                                         \
    _Pragma("unroll")                                                          \
    for (int jk = 0; jk < 4; jk++) {                                           \
      uint32_t x0 = PK[(2 * jk) * 2 + 0], y0 = PK[(2 * jk + 1) * 2 + 0];       \
      uint32_t x1 = PK[(2 * jk) * 2 + 1], y1 = PK[(2 * jk + 1) * 2 + 1];       \
      asm("v_permlane32_swap_b32 %0, %1" : "+v"(x0), "+v"(y0));                \
      asm("v_permlane32_swap_b32 %0, %1" : "+v"(x1), "+v"(y1));                \
      union { bf16x8 v; uint32_t u[4]; } pa;                                   \
      pa.u[0] = x0; pa.u[1] = x1; pa.u[2] = y0; pa.u[3] = y1;                  \
      bf16x8 v0 = *(const bf16x8*)((VB) + l31 * 144 + jk * 32 + hi * 16);      \
      bf16x8 v1 = *(const bf16x8*)((VB) + (32 + l31) * 144 + jk * 32 + hi * 16);\
      acco0 = MFMA32(pa.v, v0, acco0);                                         \
      acco1 = MFMA32(pa.v, v1, acco1);                                         \
      acco2 = MFMA32(pa.v, vones, acco2);                                      \
    }                                                                          \
  } while (0)

#define STAGE_LDS(pp)                                                          \
  do {                                                                         \
    *(int4*)((char*)Kl[pp][0] + srow * 144 + c8 * 2) = kA;                     \
    *(int4*)((char*)Kl[pp][1] + srow * 144 + c8 * 2) = kB;                     \
    *(int4*)((char*)Vl[pp][0] + srow * 144 + c8 * 2) = vA;                     \
    *(int4*)((char*)Vl[pp][1] + srow * 144 + c8 * 2) = vB;                     \
  } while (0)

#define LOADT(n)                                                               \
  do {                                                                         \
    kA = *(const int4*)(kg + (size_t)(n) * 128 * 512);                         \
    kB = *(const int4*)(kg + ((size_t)(n) * 128 + 64) * 512);                  \
    vA = *(const int4*)(vg + (n) * 128);                                       \
    vB = *(const int4*)(vg + (n) * 128 + 64);                                  \
  } while (0)

  // prologue: tile 0 -> LDS buf0; tile 1 -> regs
  int4 kA, kB, vA, vB;
  LOADT(0);
  STAGE_LDS(0);
  LOADT(1);
  __syncthreads();

  int p = 0;
  const int NT = SEQ / 128;                      // 16 tiles
  for (int jt = 0; jt < NT; jt++) {
    // ---- j-half 0 ----
    f32x16 s0 = {}, s1 = {};
    __builtin_amdgcn_s_setprio(1);
    QK_PHASE((const char*)Kl[p][0], s0, s1);
    __builtin_amdgcn_s_setprio(0);
    if (jt < NT - 1) STAGE_LDS(p ^ 1);           // overlaps SM/PV below
    {
      uint32_t pk[16];
      SM_PHASE(s0, s1, pk);
      __builtin_amdgcn_s_setprio(1);
      PV_PHASE((const char*)Vl[p][0], pk);
      __builtin_amdgcn_s_setprio(0);
    }
    // ---- j-half 1 ----
    s0 = (f32x16){}; s1 = (f32x16){};
    __builtin_amdgcn_s_setprio(1);
    QK_PHASE((const char*)Kl[p][1], s0, s1);
    __builtin_amdgcn_s_setprio(0);
    {
      uint32_t pk[16];
      SM_PHASE(s0, s1, pk);
      __builtin_amdgcn_s_setprio(1);
      PV_PHASE((const char*)Vl[p][1], pk);
      __builtin_amdgcn_s_setprio(0);
    }

    if (jt < NT - 1) {
      __syncthreads();
      if (jt < NT - 2) LOADT(jt + 2);
      p ^= 1;
    }
  }
#undef QK_PHASE
#undef SM_PHASE
#undef PV_PHASE
#undef STAGE_LDS
#undef LOADT

#pragma unroll
  for (int e = 0; e < 16; e++) {
    int qr = (e & 3) + 8 * (e >> 2) + 4 * hi;
    size_t row = base_n + q0 + w * 32 + qr;
    int col = h * 64 + l31;
    float rcp = 1.f / acco2[e];
    float v0 = acco0[e] * rcp * bf2f(gs[row * 512 + col]);
    float v1 = acco1[e] * rcp * bf2f(gs[row * 512 + col + 32]);
    gated[row * 512 + col] = f2bf(v0);
    gated[row * 512 + col + 32] = f2bf(v1);
  }
}

// ---------------------------------------------------------------------------
// LayerNorm over rows of 512, f32 in/out, wave per row.
// ---------------------------------------------------------------------------
__global__ __launch_bounds__(256) void ln_k(const float* __restrict__ y,
                                            const float* __restrict__ gamma,
                                            const float* __restrict__ beta,
                                            float* __restrict__ out) {
  int w = threadIdx.x >> 6, l = threadIdx.x & 63;
  size_t row = (size_t)blockIdx.x * 4 + w;
  const float4* yp = (const float4*)(y + row * 512);
  float4 a = yp[l * 2], b = yp[l * 2 + 1];
  float f[8] = {a.x, a.y, a.z, a.w, b.x, b.y, b.z, b.w};
  float sm = 0.f, sq = 0.f;
#pragma unroll
  for (int j = 0; j < 8; j++) { sm += f[j]; sq += f[j] * f[j]; }
#pragma unroll
  for (int off = 1; off < 64; off <<= 1) {
    sm += __shfl_xor(sm, off);
    sq += __shfl_xor(sq, off);
  }
  float mean = sm * (1.f / 512.f);
  float var = sq * (1.f / 512.f) - mean * mean;
  float rs = rsqrtf(var + 1e-5f);
  float4 g0 = ((const float4*)gamma)[l * 2], g1 = ((const float4*)gamma)[l * 2 + 1];
  float4 b0 = ((const float4*)beta)[l * 2],  b1 = ((const float4*)beta)[l * 2 + 1];
  float4 o0, o1;
  o0.x = (f[0] - mean) * rs * g0.x + b0.x;
  o0.y = (f[1] - mean) * rs * g0.y + b0.y;
  o0.z = (f[2] - mean) * rs * g0.z + b0.z;
  o0.w = (f[3] - mean) * rs * g0.w + b0.w;
  o1.x = (f[4] - mean) * rs * g1.x + b1.x;
  o1.y = (f[5] - mean) * rs * g1.y + b1.y;
  o1.z = (f[6] - mean) * rs * g1.z + b1.z;
  o1.w = (f[7] - mean) * rs * g1.w + b1.w;
  float4* op = (float4*)(out + row * 512);
  op[l * 2] = o0;
  op[l * 2 + 1] = o1;
}

// ---------------------------------------------------------------------------
extern "C" void kernel_launch(void* const* d_in, const int* in_sizes, int n_in,
                              void* d_out, int out_size, void* d_ws, size_t ws_size,
                              hipStream_t stream) {
  (void)in_sizes; (void)n_in; (void)out_size; (void)ws_size;
  const float* x     = (const float*)d_in[0];
  const float* Wq    = (const float*)d_in[1];
  const float* Wkv   = (const float*)d_in[2];
  const float* Wo    = (const float*)d_in[3];
  const float* bo    = (const float*)d_in[4];
  const float* Wg    = (const float*)d_in[5];
  const float* bg    = (const float*)d_in[6];
  const float* gamma = (const float*)d_in[7];
  const float* beta  = (const float*)d_in[8];

  char* ws = (char*)d_ws;
  ushort* xb    = (ushort*)(ws);                    //  8 MiB
  ushort* qbuf  = (ushort*)(ws + (8u  << 20));      //  8 MiB
  ushort* kbuf  = (ushort*)(ws + (16u << 20));      //  8 MiB
  ushort* vT    = (ushort*)(ws + (32u << 20));      //  8 MiB [bh][64][2048]
  ushort* gsb   = (ushort*)(ws + (40u << 20));      //  8 MiB
  ushort* gated = (ushort*)(ws + (48u << 20));      //  8 MiB
  float*  y     = (float*)(ws + (56u << 20));       // 16 MiB
  ushort* WT    = (ushort*)(ws + (72u << 20));      //  2 MiB  [2048][512]
  ushort* WoT   = (ushort*)(ws + (74u << 20));      // 0.5 MiB

  // fused x-convert + weight transposes (concurrent)
  prep_k<<<2048 + 1280, 256, 0, stream>>>(x, Wq, Wkv, Wg, Wo, xb, WT, WoT);

  // fused q/k/v/gates projection: [8192,512] @ [2048,512]^T, 128^2 tiles.
  // V panel lands directly transposed in vT (no vtrans kernel).
  gemm128_k<<<dim3(16, 64), 256, 0, stream>>>(xb, WT, qbuf, kbuf, vT, gsb, bg);

  attn_k<<<256, 512, 0, stream>>>(qbuf, kbuf, vT, gsb, gated);

  // out-projection: 128x64 tiles -> 512 blocks = 2 blocks/CU
  gemm_o_k<<<dim3(8, 64), 256, 0, stream>>>(gated, WoT, y, bo, x);

  ln_k<<<(NBATCH * SEQ) / 4, 256, 0, stream>>>(y, gamma, beta, (float*)d_out);
}